// Round 3
// baseline (3196.746 us; speedup 1.0000x reference)
//
#include <hip/hip_runtime.h>
#include <hip/hip_bf16.h>

typedef __hip_bfloat16 bf16;

#define N_NODES 50000
#define N_EDGES 400000
#define IN_DIM  256
#define EDGE_F  64
#define OUT_DIM 32
#define EDGE_OUT 64
#define NHEADS  8
#define HD      256   // NHEADS*OUT_DIM
#define ALPHA   0.2f
#define BN_EPS  1e-5f

__device__ __forceinline__ float b2f(bf16 v){ return __bfloat162float(v); }
__device__ __forceinline__ bf16  f2b(float v){ return __float2bfloat16(v); }
__device__ __forceinline__ float lrelu(float x){ return x > 0.f ? x : ALPHA*x; }
__device__ __forceinline__ unsigned fenc(float f){ unsigned u=__float_as_uint(f); return (u&0x80000000u)? ~u : (u|0x80000000u); }
__device__ __forceinline__ float fdec(unsigned k){ return (k&0x80000000u)? __uint_as_float(k&0x7fffffffu) : __uint_as_float(~k); }
__device__ __forceinline__ float blo(unsigned wp){ return __uint_as_float(wp<<16); }
__device__ __forceinline__ float bhi(unsigned wp){ return __uint_as_float(wp & 0xffff0000u); }

// dtype-adaptive load/store: F32=true -> fp32 buffer, else bf16 buffer
template<bool F32> __device__ __forceinline__ float LD(const void* p, long i){
  if constexpr (F32) return ((const float*)p)[i];
  else               return b2f(((const bf16*)p)[i]);
}
template<bool F32> __device__ __forceinline__ void ST(void* p, long i, float v){
  if constexpr (F32) ((float*)p)[i] = v;
  else               ((bf16*)p)[i] = f2b(v);
}
// consecutive pair (2i,2i+1) packed as two bf16 in a uint (lo = element 2i)
template<bool F32> __device__ __forceinline__ unsigned LDpair(const void* p, long i){
  if constexpr (F32){
    bf16 L = f2b(((const float*)p)[2*i]);
    bf16 H = f2b(((const float*)p)[2*i+1]);
    return ((unsigned)(*(unsigned short*)&H) << 16) | (unsigned)(*(unsigned short*)&L);
  } else return ((const unsigned*)p)[i];
}
// edge-section base inside d_out: skip N*HD elements of the flag-selected dtype
template<bool F32> __device__ __forceinline__ void* ESEC(void* out){
  return (char*)out + (size_t)N_NODES*HD*(F32?4:2);
}

// ---- K0: input-dtype detector (fp32 viewed as u16 shows absurd bf16 exponents) ----
__global__ __launch_bounds__(256) void k_detect(const unsigned short* __restrict__ u,
                                                int* __restrict__ flag){
  __shared__ int cnt;
  if(threadIdx.x==0) cnt=0;
  __syncthreads();
  int local=0;
  for(int i=threadIdx.x;i<8192;i+=256){
    int e = (u[i]>>7)&0xFF;
    if(e>=200) local++;               // |x| >= 2^73: impossible for N(0,1) data
  }
  atomicAdd(&cnt, local);
  __syncthreads();
  if(threadIdx.x==0) *flag = (cnt>64) ? 1 : 0;   // 1 => buffers are fp32
}

// ---------------- K1: ft = node_inputs @ fc_w -> d_out node section ----------------
template<bool F32> __device__ void node_proj_body(const void* x, const void* w,
                                                  void* ft, float* sx){
  int n0 = blockIdx.x * 8;
  int t  = threadIdx.x;
  #pragma unroll
  for(int r=0;r<8;r++) sx[t*8+r] = LD<F32>(x,(long)(n0+r)*IN_DIM + t);
  __syncthreads();
  float acc[8] = {0,0,0,0,0,0,0,0};
  #pragma unroll 4
  for(int k=0;k<IN_DIM;k++){
    float wv = LD<F32>(w,(long)k*HD + t);
    const float4 u0 = *(const float4*)&sx[k*8];
    const float4 u1 = *(const float4*)&sx[k*8+4];
    acc[0] += u0.x*wv; acc[1] += u0.y*wv; acc[2] += u0.z*wv; acc[3] += u0.w*wv;
    acc[4] += u1.x*wv; acc[5] += u1.y*wv; acc[6] += u1.z*wv; acc[7] += u1.w*wv;
  }
  #pragma unroll
  for(int r=0;r<8;r++) ST<F32>(ft,(long)(n0+r)*HD + t, acc[r]);
}
__global__ __launch_bounds__(256) void k_node_proj(const void* x, const void* w,
                                                   void* ft, const int* flag){
  extern __shared__ float smemf[];
  if(*flag) node_proj_body<true >(x,w,ft,smemf);
  else      node_proj_body<false>(x,w,ft,smemf);
}

// ---------------- K2: a1/a2 per-(node,head) dots ----------------
template<bool F32> __device__ void attn_body(const void* ft, const void* al, const void* ar,
                                             float* a1, float* a2){
  int gid = blockIdx.x*8 + (threadIdx.x>>5);
  int d   = threadIdx.x & 31;
  int h   = gid & 7;
  float v  = LD<F32>(ft,(long)gid*OUT_DIM + d);
  float s1 = v * LD<F32>(al, h*OUT_DIM + d);
  float s2 = v * LD<F32>(ar, h*OUT_DIM + d);
  for(int o=16;o>0;o>>=1){ s1 += __shfl_down(s1,o,32); s2 += __shfl_down(s2,o,32); }
  if(d==0){ a1[gid]=s1; a2[gid]=s2; }
}
__global__ __launch_bounds__(256) void k_attn(const void* ft, const void* al, const void* ar,
                                              float* a1, float* a2, const int* flag){
  if(*flag) attn_body<true >(ft,al,ar,a1,a2);
  else      attn_body<false>(ft,al,ar,a1,a2);
}

// ---------------- K3: edge-attn MLP + lrelu + segment-max ----------------
template<bool F32> __device__ void edge_attn_body(const void* ein, const void* w1, const void* b1,
                                                  const void* w2, const void* b2,
                                                  const float* a1, const float* a2,
                                                  const int* src, const int* dst,
                                                  float* a_edge, unsigned* amax, float* sm){
  float* sw1 = sm;            // 2048
  float* sw2 = sw1 + 2048;    // 256
  float* sb1 = sw2 + 256;     // 32
  float* sb2 = sb1 + 32;      // 8
  float* se  = sb2 + 8;       // 8*64
  float* st  = se  + 512;     // 8*32
  int t = threadIdx.x;
  #pragma unroll
  for(int i=0;i<8;i++) sw1[i*256+t] = LD<F32>(w1, i*256+t);
  sw2[t] = LD<F32>(w2, t);
  if(t<OUT_DIM) sb1[t]=LD<F32>(b1,t);
  if(t<NHEADS)  sb2[t]=LD<F32>(b2,t);
  int e0 = blockIdx.x*8;
  #pragma unroll
  for(int i=0;i<2;i++){ int idx=i*256+t; se[idx] = LD<F32>(ein,(long)e0*EDGE_F + idx); }
  __syncthreads();
  int r = t>>5, j = t&31;
  float acc = sb1[j];
  #pragma unroll 4
  for(int k=0;k<EDGE_F;k++) acc += se[r*64+k]*sw1[k*OUT_DIM+j];
  st[r*32+j] = lrelu(acc);
  __syncthreads();
  if(t<64){
    int rr = t>>3, h = t&7;
    float s = sb2[h];
    #pragma unroll
    for(int jj=0;jj<OUT_DIM;jj++) s += st[rr*32+jj]*sw2[jj*NHEADS+h];
    int e = e0+rr;
    int sv = src[e], dv = dst[e];
    float av = lrelu(a1[sv*NHEADS+h] + a2[dv*NHEADS+h] + s);   // TEMP==1
    a_edge[(long)e*NHEADS+h] = av;
    atomicMax(&amax[dv*NHEADS+h], fenc(av));
  }
}
__global__ __launch_bounds__(256) void k_edge_attn(const void* ein, const void* w1, const void* b1,
                                                   const void* w2, const void* b2,
                                                   const float* a1, const float* a2,
                                                   const int* src, const int* dst,
                                                   float* a_edge, unsigned* amax, const int* flag){
  extern __shared__ float smemf[];
  if(*flag) edge_attn_body<true >(ein,w1,b1,w2,b2,a1,a2,src,dst,a_edge,amax,smemf);
  else      edge_attn_body<false>(ein,w1,b1,w2,b2,a1,a2,src,dst,a_edge,amax,smemf);
}

// ---------------- K4: softmax numerators, z, weighted aggregation ----------------
template<bool F32> __device__ void soft_agg_body(const void* ft, const float* a_edge,
                                                 const unsigned* amax,
                                                 const int* src, const int* dst,
                                                 float* z, float* agg, float* sav){
  int w = threadIdx.x>>6, lane = threadIdx.x&63;
  int e = blockIdx.x*4 + w;
  int sv = src[e], dv = dst[e];
  if(lane < NHEADS){
    float av = __expf(a_edge[(long)e*NHEADS+lane] - fdec(amax[dv*NHEADS+lane]));
    unsafeAtomicAdd(&z[dv*NHEADS+lane], av);
    sav[w*NHEADS+lane] = av;
  }
  __syncthreads();
  long fbase = (long)sv*HD;
  float* aggp = agg + (size_t)dv*HD;
  #pragma unroll
  for(int q=0;q<4;q++){
    int j = lane + 64*q;
    unsafeAtomicAdd(&aggp[j], LD<F32>(ft, fbase+j)*sav[w*NHEADS+(j>>5)]);
  }
}
__global__ __launch_bounds__(256) void k_soft_agg(const void* ft, const float* a_edge,
                                                  const unsigned* amax,
                                                  const int* src, const int* dst,
                                                  float* z, float* agg, const int* flag){
  __shared__ float sav[4*NHEADS];
  if(*flag) soft_agg_body<true >(ft,a_edge,amax,src,dst,z,agg,sav);
  else      soft_agg_body<false>(ft,a_edge,amax,src,dst,z,agg,sav);
}

// ---------------- K5: residual + lrelu -> pre-BN x into d_out node section; stats ----------------
template<bool F32> __device__ void node_stage_body(const float* agg, const float* z,
                                                   const void* xin, void* xout, double* dstats){
  int t = threadIdx.x;
  double s=0.0, q=0.0;
  for(int n=blockIdx.x; n<N_NODES; n+=gridDim.x){
    float zz = z[n*NHEADS + (t>>5)];
    float zs = (zz==0.f) ? 1.f : zz;
    float x  = lrelu(agg[(long)n*HD+t]/zs + LD<F32>(xin,(long)n*HD+t));
    ST<F32>(xout,(long)n*HD+t, x);
    s += x; q += (double)x*(double)x;
  }
  unsafeAtomicAdd(&dstats[t],    s);
  unsafeAtomicAdd(&dstats[HD+t], q);
}
__global__ __launch_bounds__(256) void k_node_stage(const float* agg, const float* z,
                                                    const void* xin, void* xout,
                                                    double* dstats, const int* flag){
  if(*flag) node_stage_body<true >(agg,z,xin,xout,dstats);
  else      node_stage_body<false>(agg,z,xin,xout,dstats);
}

// ---------------- BN params from double sums ----------------
template<bool F32> __device__ void bn_params_body(const double* dstats, const void* g,
                                                  const void* b, float* scsh, int C, double invM){
  int t = threadIdx.x;
  if(t>=C) return;
  double mu  = dstats[t]*invM;
  double var = dstats[C+t]*invM - mu*mu;
  if(var < 0.0) var = 0.0;
  float sc = LD<F32>(g,t) * rsqrtf((float)var + BN_EPS);
  scsh[t]   = sc;
  scsh[C+t] = LD<F32>(b,t) - (float)mu*sc;
}
__global__ void k_bn_params(const double* dstats, const void* g, const void* b,
                            float* scsh, int C, double invM, const int* flag){
  if(*flag) bn_params_body<true >(dstats,g,b,scsh,C,invM);
  else      bn_params_body<false>(dstats,g,b,scsh,C,invM);
}

// ---------------- K6: node BN apply, in place on d_out node section ----------------
template<bool F32> __device__ void node_apply_body(void* x, const float* scsh){
  int t = threadIdx.x;
  float sc = scsh[t], sh = scsh[HD+t];
  for(long i=(long)blockIdx.x*256+t; i<(long)N_NODES*HD; i+=(long)gridDim.x*256){
    ST<F32>(x, i, fmaf(LD<F32>(x,i), sc, sh));
  }
}
__global__ __launch_bounds__(256) void k_node_apply(void* x, const float* scsh, const int* flag){
  if(*flag) node_apply_body<true >(x,scsh);
  else      node_apply_body<false>(x,scsh);
}

// ---------------- K7: fused edge update -> pre-BN edge into d_out edge section ----------------
template<bool F32> __device__ void edge_update_body(const void* nodeb, const void* edge_in,
                                                    const int* src, const int* dst,
                                                    const void* wn, const void* we, const void* wf,
                                                    void* d_out, char* sm){
  void* edge_x = ESEC<F32>(d_out);
  unsigned* swn = (unsigned*)sm;          // 8192 uints (32KB)
  float* suv = (float*)(swn + 8192);      // 8*512
  float* se_ = suv + 4096;                // 8*64
  float* sfe = se_ + 512;                 // 8*128
  int* ssrc  = (int*)(sfe + 1024);        // 8
  int* sdst  = ssrc + 8;                  // 8
  int tid = threadIdx.x;
  int e0  = blockIdx.x*8;
  if(tid<8){ ssrc[tid]=src[e0+tid]; sdst[tid]=dst[e0+tid]; }
  for(int i=tid;i<512;i+=256) se_[i] = LD<F32>(edge_in,(long)e0*EDGE_F + i);
  for(int i=tid;i<8192;i+=256) swn[i] = LDpair<F32>(wn, i);          // Wn rows 0..255
  __syncthreads();
  for(int i=tid;i<4096;i+=256){
    int r=i>>9, c=i&511;
    int node = (c<256) ? ssrc[r] : sdst[r];
    suv[r*512+c] = LD<F32>(nodeb,(long)node*HD + (c&255));
  }
  __syncthreads();
  int r = tid>>5, t = tid&31;
  float a0=0.f, a1v=0.f;
  #pragma unroll 4
  for(int k=0;k<256;k++){
    unsigned wp = swn[k*32+t];
    float u = suv[r*512+k];
    a0  = fmaf(u, blo(wp), a0);
    a1v = fmaf(u, bhi(wp), a1v);
  }
  __syncthreads();
  for(int i=tid;i<8192;i+=256) swn[i] = LDpair<F32>(wn, 8192+i);     // Wn rows 256..511
  __syncthreads();
  #pragma unroll 4
  for(int k=0;k<256;k++){
    unsigned wp = swn[k*32+t];
    float u = suv[r*512+k+256];
    a0  = fmaf(u, blo(wp), a0);
    a1v = fmaf(u, bhi(wp), a1v);
  }
  sfe[r*128+2*t]   = lrelu(a0);
  sfe[r*128+2*t+1] = lrelu(a1v);
  __syncthreads();
  for(int i=tid;i<6144;i+=256) swn[i] = (i<2048) ? LDpair<F32>(we,i) : LDpair<F32>(wf,i-2048);
  __syncthreads();
  float b0=0.f, b1v=0.f;
  #pragma unroll 4
  for(int k=0;k<64;k++){
    unsigned wp = swn[k*32+t];
    float u = se_[r*64+k];
    b0  = fmaf(u, blo(wp), b0);
    b1v = fmaf(u, bhi(wp), b1v);
  }
  sfe[r*128+64+2*t]   = lrelu(b0);
  sfe[r*128+64+2*t+1] = lrelu(b1v);
  __syncthreads();
  float c0=0.f, c1v=0.f;
  #pragma unroll 4
  for(int k=0;k<128;k++){
    unsigned wp = swn[2048 + k*32+t];
    float u = sfe[r*128+k];
    c0  = fmaf(u, blo(wp), c0);
    c1v = fmaf(u, bhi(wp), c1v);
  }
  long e = e0 + r;
  ST<F32>(edge_x, e*EDGE_OUT + 2*t,   lrelu(c0  + se_[r*64+2*t]));
  ST<F32>(edge_x, e*EDGE_OUT + 2*t+1, lrelu(c1v + se_[r*64+2*t+1]));
}
__global__ __launch_bounds__(256) void k_edge_update(const void* nodeb, const void* edge_in,
                                                     const int* src, const int* dst,
                                                     const void* wn, const void* we, const void* wf,
                                                     void* d_out, const int* flag){
  extern __shared__ char smemc[];
  if(*flag) edge_update_body<true >(nodeb,edge_in,src,dst,wn,we,wf,d_out,smemc);
  else      edge_update_body<false>(nodeb,edge_in,src,dst,wn,we,wf,d_out,smemc);
}

// ---------------- K8: edge column stats ----------------
template<bool F32> __device__ void edge_stats_body(void* d_out, double* dstats, double* sm){
  const void* ex = ESEC<F32>(d_out);
  double* ls = sm; double* lq = sm+256;
  int t = threadIdx.x;
  int c = t & 63, r0 = t >> 6;
  double s=0.0, q=0.0;
  for(long i=(long)(blockIdx.x*4 + r0)*64 + c; i < (long)N_EDGES*EDGE_OUT; i += (long)gridDim.x*4*64){
    float x = LD<F32>(ex, i);
    s += x; q += (double)x*(double)x;
  }
  ls[t]=s; lq[t]=q;
  __syncthreads();
  if(t<64){
    double ss = ls[t]+ls[t+64]+ls[t+128]+ls[t+192];
    double qq = lq[t]+lq[t+64]+lq[t+128]+lq[t+192];
    unsafeAtomicAdd(&dstats[t], ss);
    unsafeAtomicAdd(&dstats[64+t], qq);
  }
}
__global__ __launch_bounds__(256) void k_edge_stats(void* d_out, double* dstats, const int* flag){
  extern __shared__ double smemd[];
  if(*flag) edge_stats_body<true >(d_out,dstats,smemd);
  else      edge_stats_body<false>(d_out,dstats,smemd);
}

// ---------------- K9: edge BN apply, in place on d_out edge section ----------------
template<bool F32> __device__ void edge_apply_body(void* d_out, const float* scsh){
  void* ex = ESEC<F32>(d_out);
  int t = threadIdx.x;
  int c = t & 63;
  float sc = scsh[c], sh = scsh[64+c];
  for(long i=(long)blockIdx.x*256+t; i<(long)N_EDGES*EDGE_OUT; i+=(long)gridDim.x*256){
    ST<F32>(ex, i, fmaf(LD<F32>(ex,i), sc, sh));
  }
}
__global__ __launch_bounds__(256) void k_edge_apply(void* d_out, const float* scsh, const int* flag){
  if(*flag) edge_apply_body<true >(d_out,scsh);
  else      edge_apply_body<false>(d_out,scsh);
}

extern "C" void kernel_launch(void* const* d_in, const int* in_sizes, int n_in,
                              void* d_out, int out_size, void* d_ws, size_t ws_size,
                              hipStream_t stream){
  const void* node_in    = d_in[0];
  const void* edge_in    = d_in[1];
  const void* fc_w       = d_in[2];
  const void* attn_l     = d_in[3];
  const void* attn_r     = d_in[4];
  const void* ae_w1      = d_in[5];
  const void* ae_b1      = d_in[6];
  const void* ae_w2      = d_in[7];
  const void* ae_b2      = d_in[8];
  const void* bn_n_g     = d_in[9];
  const void* bn_n_b     = d_in[10];
  const void* eu_node_w  = d_in[11];
  const void* eu_edge_w  = d_in[12];
  const void* eu_final_w = d_in[13];
  const void* bn_e_g     = d_in[14];
  const void* bn_e_b     = d_in[15];
  const int*  src        = (const int*)d_in[16];
  const int*  dst        = (const int*)d_in[17];

  // ---- workspace (~70.4 MB) ----
  char* base = (char*)d_ws;
  double*   dstats_n = (double*)base;                 // 512 dbl
  double*   dstats_e = (double*)(base + 4096);        // 128 dbl
  float*    scsh_n   = (float*)(base + 5120);         // 512 f
  float*    scsh_e   = (float*)(base + 7168);         // 128 f
  int*      flag     = (int*)(base + 7680);
  char*     big      = base + 8192;
  float*    aggb     = (float*)big;                   // N*HD f32 = 51.2MB
  float*    a_edge   = (float*)(big + 51200000);      // E*8  f32 = 12.8MB
  float*    a1       = (float*)(big + 64000000);      // N*8
  float*    a2       = (float*)(big + 65600000);      // N*8
  unsigned* amax     = (unsigned*)(big + 67200000);   // N*8
  float*    zb       = (float*)(big + 68800000);      // N*8  (ends ~70.4MB)

  hipMemsetAsync(dstats_n, 0, 640*sizeof(double), stream);
  hipMemsetAsync(aggb, 0, (size_t)N_NODES*HD*sizeof(float), stream);
  hipMemsetAsync(amax, 0, (size_t)N_NODES*NHEADS*2*sizeof(unsigned), stream); // amax + zb

  k_detect<<<1, 256, 0, stream>>>((const unsigned short*)node_in, flag);
  k_node_proj<<<N_NODES/8, 256, 8192, stream>>>(node_in, fc_w, d_out, flag);
  k_attn<<<N_NODES*NHEADS/8, 256, 0, stream>>>(d_out, attn_l, attn_r, a1, a2, flag);
  k_edge_attn<<<N_EDGES/8, 256, 12448, stream>>>(edge_in, ae_w1, ae_b1, ae_w2, ae_b2,
                                                 a1, a2, src, dst, a_edge, amax, flag);
  k_soft_agg<<<N_EDGES/4, 256, 0, stream>>>(d_out, a_edge, amax, src, dst, zb, aggb, flag);
  k_node_stage<<<512, 256, 0, stream>>>(aggb, zb, node_in, d_out, dstats_n, flag);
  k_bn_params<<<1, 256, 0, stream>>>(dstats_n, bn_n_g, bn_n_b, scsh_n, HD, 1.0/N_NODES, flag);
  k_node_apply<<<2048, 256, 0, stream>>>(d_out, scsh_n, flag);
  k_edge_update<<<N_EDGES/8, 256, 55360, stream>>>(d_out, edge_in, src, dst,
                                                   eu_node_w, eu_edge_w, eu_final_w,
                                                   d_out, flag);
  k_edge_stats<<<512, 256, 4096, stream>>>(d_out, dstats_e, flag);
  k_bn_params<<<1, 256, 0, stream>>>(dstats_e, bn_e_g, bn_e_b, scsh_e, EDGE_OUT, 1.0/N_EDGES, flag);
  k_edge_apply<<<2048, 256, 0, stream>>>(d_out, scsh_e, flag);
  (void)ws_size; (void)out_size; (void)n_in; (void)in_sizes;
}